// Round 5
// baseline (354.702 us; speedup 1.0000x reference)
//
#include <hip/hip_runtime.h>

// ---------------------------------------------------------------- constants
#define TTOK 32768
#define DM   256
#define NF   1024
#define KMAX 32

typedef __attribute__((ext_vector_type(8))) unsigned short ushort8;
typedef __attribute__((ext_vector_type(8))) __bf16 bf16x8;
typedef __attribute__((ext_vector_type(4))) float floatx4;

// workspace offsets (all 256B aligned)
constexpr size_t O_SLOT = 0;                                   // 1 uint (max|Wt|)
constexpr size_t O_S    = 256;                                 // 1024 f32 sigmoid(alpha)
constexpr size_t O_WCT  = O_S    + 4096;                       // Wc^T  [1024][256] bf16
constexpr size_t O_WGT  = O_WCT  + (size_t)NF*DM*2;            // Wg^T  [1024][256] bf16
constexpr size_t O_WDT  = O_WGT  + (size_t)NF*DM*2;            // Wd^T  [256][1024] bf16
constexpr size_t O_WTT  = O_WDT  + (size_t)DM*NF*2;            // Wt^T  [256][1024] f32
constexpr size_t O_XBF  = O_WTT  + (size_t)DM*NF*4;            // x bf16 [T][256]
constexpr size_t O_CNT  = O_XBF  + (size_t)TTOK*DM*2;          // counts [T]
constexpr size_t O_CIDX = O_CNT  + (size_t)TTOK*4;             // cand off(d*NF) [T][KMAX]
constexpr size_t O_CVAL = O_CIDX + (size_t)TTOK*KMAX*4;        // cand val [T][KMAX]
constexpr size_t O_FUSD = O_CVAL + (size_t)TTOK*KMAX*4;        // fused bf16 [T][1024]

__device__ __forceinline__ float bf2f(unsigned short u) {
    union { unsigned int i; float f; } c; c.i = ((unsigned int)u) << 16; return c.f;
}
__device__ __forceinline__ unsigned short f2bf(float v) {
    union { float f; unsigned int i; } c; c.f = v;
    unsigned int b = c.i;
    return (unsigned short)((b + 0x7FFFu + ((b >> 16) & 1u)) >> 16);
}
__device__ __forceinline__ float sigm(float z) { return 1.0f / (1.0f + __expf(-z)); }
// tanh-gelu: max |diff| vs exact erf-gelu ~3e-3, far under 0.266 tolerance
__device__ __forceinline__ float gelu_f(float x) {
    return x * sigm(1.59576912f * (x + 0.044715f * x * x * x));
}
// async global->LDS, 16B per lane; lds dest = wave-uniform base + lane*16 [m97/m104]
__device__ __forceinline__ void g2lds16(const unsigned short* g, unsigned short* l) {
    __builtin_amdgcn_global_load_lds((const __attribute__((address_space(1))) unsigned int*)g,
                                     (__attribute__((address_space(3))) unsigned int*)l, 16, 0, 0);
}

// ------------------------------------------------- kernel 1: pack weights
__global__ void pack_kernel(const float* __restrict__ Wt, const float* __restrict__ alpha,
                            const float* __restrict__ Wc, const float* __restrict__ Wg,
                            const float* __restrict__ Wd,
                            unsigned short* __restrict__ Wct, unsigned short* __restrict__ Wgt,
                            unsigned short* __restrict__ WdT, float* __restrict__ WtT,
                            float* __restrict__ s, unsigned int* __restrict__ slot) {
    int e = blockIdx.x * 256 + threadIdx.x;
    if (e == 0) *slot = 0u;
    { int f = e >> 8, k = e & 255;           // Wc/Wg are [256][1024]
      Wct[e] = f2bf(Wc[k * NF + f]);
      Wgt[e] = f2bf(Wg[k * NF + f]); }
    { int n = e >> 10, k = e & 1023;         // Wd is [1024][256]
      WdT[e] = f2bf(Wd[k * DM + n]); }
    { int d = e >> 10, f = e & 1023;         // Wt is [1024][256]
      WtT[e] = Wt[f * DM + d]; }
    if (e < NF) s[e] = sigm(alpha[e]);
}

// ------------------------------------------------- kernel 2: max|Wt| reduce
__global__ void minmax_kernel(const float* __restrict__ Wt, unsigned int* __restrict__ slot) {
    int g = blockIdx.x * 256 + threadIdx.x;
    float lm = 0.0f;
    for (int i = g; i < NF * DM; i += 128 * 256) lm = fmaxf(lm, fabsf(Wt[i]));
    #pragma unroll
    for (int o = 32; o > 0; o >>= 1) lm = fmaxf(lm, __shfl_xor(lm, o));
    if ((threadIdx.x & 63) == 0) atomicMax(slot, __float_as_uint(lm)); // |w|>=0: uint order ok
}

// ------------------------------------------------- kernel 3: candidates + x->bf16
__global__ void cand_kernel(const float* __restrict__ x, const unsigned int* __restrict__ slot,
                            unsigned short* __restrict__ xbf, int* __restrict__ counts,
                            int* __restrict__ cidx, float* __restrict__ cval) {
    int i = blockIdx.x, t = threadIdx.x;
    float v = x[i * DM + t];
    xbf[i * DM + t] = f2bf(v);
    float m = v;
    #pragma unroll
    for (int o = 32; o > 0; o >>= 1) m = fmaxf(m, __shfl_xor(m, o));
    __shared__ float wm[4];
    __shared__ int cnt;
    __shared__ int sidx[KMAX];
    __shared__ float sval[KMAX];
    if ((t & 63) == 0) wm[t >> 6] = m;
    if (t == 0) cnt = 0;
    __syncthreads();
    float xmax = fmaxf(fmaxf(wm[0], wm[1]), fmaxf(wm[2], wm[3]));
    float delta = 2.0f * __uint_as_float(*slot);   // >= Wmax - Wmin : exact exclusion bound
    float thr = xmax - delta;
    if (v >= thr) {
        int p = atomicAdd(&cnt, 1);
        if (p < KMAX) { sidx[p] = t * NF; sval[p] = v; }   // premultiplied row offset
    }
    __syncthreads();
    int c = cnt;
    if (t == 0) counts[i] = c;
    if (t < (c < KMAX ? c : KMAX)) {
        cidx[i * KMAX + t] = sidx[t];
        cval[i * KMAX + t] = sval[t];
    }
}

// ------------------------------------------------- kernel 4: fused GEMM1
// (x@Wc, x@Wg) via MFMA + tropical max-plus + convex/concave + gate blend, all
// in one kernel. 128x128 tile, BK=32, 512 thr (8 waves 2Mx4F, wave 64x32 dual).
// Candidate meta staged to LDS PRE-PADDED (off=0,val=-1e30 => branchless k-loop),
// row stride 33 pairs so the 4 quads (m, m+4, m+8, m+12) hit different banks.
// WtT gather: 16 lr-lanes read consecutive f -> 64B segments (L2-resident Wt).
#define LDSS 32   // ushorts per LDS row, no pad (wave-uniform-base DMA, m104)
#define KPAD 33
__global__ __launch_bounds__(512, 4) void gemm1_kernel(
    const unsigned short* __restrict__ A,   // xbf [T][256]
    const unsigned short* __restrict__ Bct, // [1024][256]
    const unsigned short* __restrict__ Bgt, // [1024][256]
    const float* __restrict__ bc, const float* __restrict__ bg,
    const int* __restrict__ counts, const int* __restrict__ cidx,
    const float* __restrict__ cval, const float* __restrict__ x,
    const float* __restrict__ WtT, const float* __restrict__ bt,
    const float* __restrict__ slx, const float* __restrict__ ofx,
    const float* __restrict__ slc, const float* __restrict__ ofc,
    const float* __restrict__ s, unsigned short* __restrict__ fused) {
    __shared__ __align__(16) unsigned short As[128 * LDSS];
    __shared__ __align__(16) unsigned short Bcs[128 * LDSS];
    __shared__ __align__(16) unsigned short Bgs[128 * LDSS];
    __shared__ __align__(8) int sOV[128 * KPAD * 2];   // (off, val-bits) pairs
    __shared__ int sCnt[128];
    const int t = threadIdx.x;
    const int bm = blockIdx.x, bf = blockIdx.y;
    const int wave = t >> 6, lane = t & 63;
    const int wm = wave & 1, wn = wave >> 1;
    const int lr = lane & 15, quad = lane >> 4;
    const int srow = wave * 16 + (lane >> 2), scol = (lane & 3) << 3;
    const unsigned short* gA = A   + (size_t)(bm * 128 + srow) * DM + scol;
    const unsigned short* gC = Bct + (size_t)(bf * 128 + srow) * DM + scol;
    const unsigned short* gG = Bgt + (size_t)(bf * 128 + srow) * DM + scol;
    unsigned short* lA = &As[wave * 16 * LDSS];
    unsigned short* lC = &Bcs[wave * 16 * LDSS];
    unsigned short* lG = &Bgs[wave * 16 * LDSS];

    // ---- stage candidate meta (pre-padded) ----
    if (t < 128) sCnt[t] = counts[bm * 128 + t];
    for (int e = t; e < 128 * KMAX; e += 512) {
        int m = e >> 5, k = e & 31;
        int c = counts[bm * 128 + m];
        int off = 0; float val = -1e30f;
        if (k < (c < KMAX ? c : KMAX)) {
            off = cidx[(size_t)(bm * 128 + m) * KMAX + k];
            val = cval[(size_t)(bm * 128 + m) * KMAX + k];
        }
        sOV[(m * KPAD + k) * 2]     = off;
        sOV[(m * KPAD + k) * 2 + 1] = __float_as_int(val);
    }

    floatx4 accc[4][2], accg[4][2];
    #pragma unroll
    for (int i = 0; i < 4; i++)
        #pragma unroll
        for (int j = 0; j < 2; j++) { accc[i][j] = (floatx4)0.0f; accg[i][j] = (floatx4)0.0f; }

    for (int k0 = 0; k0 < DM; k0 += 32) {
        __syncthreads();            // covers sOV stage (1st iter) + prior ds_reads
        g2lds16(gA + k0, lA);
        g2lds16(gC + k0, lC);
        g2lds16(gG + k0, lG);
        __syncthreads();
        bf16x8 af[4], bcf[2], bgf[2];
        #pragma unroll
        for (int mi = 0; mi < 4; mi++)
            af[mi] = *(const bf16x8*)&As[(wm * 64 + mi * 16 + lr) * LDSS + quad * 8];
        #pragma unroll
        for (int ni = 0; ni < 2; ni++) {
            bcf[ni] = *(const bf16x8*)&Bcs[(wn * 32 + ni * 16 + lr) * LDSS + quad * 8];
            bgf[ni] = *(const bf16x8*)&Bgs[(wn * 32 + ni * 16 + lr) * LDSS + quad * 8];
        }
        #pragma unroll
        for (int mi = 0; mi < 4; mi++)
            #pragma unroll
            for (int ni = 0; ni < 2; ni++) {
                accc[mi][ni] = __builtin_amdgcn_mfma_f32_16x16x32_bf16(af[mi], bcf[ni], accc[mi][ni], 0, 0, 0);
                accg[mi][ni] = __builtin_amdgcn_mfma_f32_16x16x32_bf16(af[mi], bgf[ni], accg[mi][ni], 0, 0, 0);
            }
    }
    // no barrier needed: sOV written pre-loop, never overwritten

    // ---- fused epilogue: tropical z + convex/concave + gate blend ----
    // C/D layout col=lane&15, row=quad*4+r  [verified m89/m91]
    #pragma unroll
    for (int mi = 0; mi < 4; mi++) {
        const int mb = wm * 64 + mi * 16 + quad * 4;   // local m of r=0
        int c0 = sCnt[mb], c1 = sCnt[mb + 1], c2 = sCnt[mb + 2], c3 = sCnt[mb + 3];
        int k0c = c0 < KMAX ? c0 : KMAX, k1c = c1 < KMAX ? c1 : KMAX;
        int k2c = c2 < KMAX ? c2 : KMAX, k3c = c3 < KMAX ? c3 : KMAX;
        int km = max(max(k0c, k1c), max(k2c, k3c));
        #pragma unroll
        for (int ni = 0; ni < 2; ni++) {
            const int f = bf * 128 + wn * 32 + ni * 16 + lr;
            // tropical max-plus for the 4 r's, interleaved (8 loads in flight)
            float z0 = -1e30f, z1 = -1e30f, z2 = -1e30f, z3 = -1e30f;
            for (int k = 0; k < km; k++) {
                int2 p0 = *(const int2*)&sOV[((mb + 0) * KPAD + k) * 2];
                int2 p1 = *(const int2*)&sOV[((mb + 1) * KPAD + k) * 2];
                int2 p2 = *(const int2*)&sOV[((mb + 2) * KPAD + k) * 2];
                int2 p3 = *(const int2*)&sOV[((mb + 3) * KPAD + k) * 2];
                float w0 = WtT[p0.x + f];
                float w1 = WtT[p1.x + f];
                float w2 = WtT[p2.x + f];
                float w3 = WtT[p3.x + f];
                z0 = fmaxf(z0, __int_as_float(p0.y) + w0);
                z1 = fmaxf(z1, __int_as_float(p1.y) + w1);
                z2 = fmaxf(z2, __int_as_float(p2.y) + w2);
                z3 = fmaxf(z3, __int_as_float(p3.y) + w3);
            }
            // exact fallback (never expected): full 256-d scan
            if (c0 > KMAX || c1 > KMAX || c2 > KMAX || c3 > KMAX) {
                float zz[4] = { z0, z1, z2, z3 };
                int cc[4] = { c0, c1, c2, c3 };
                #pragma unroll 1
                for (int r = 0; r < 4; r++) if (cc[r] > KMAX) {
                    const float* xr = x + (size_t)(bm * 128 + mb + r) * DM;
                    float m2 = -1e30f;
                    for (int d = 0; d < DM; d++) m2 = fmaxf(m2, xr[d] + WtT[d * NF + f]);
                    zz[r] = m2;
                }
                z0 = zz[0]; z1 = zz[1]; z2 = zz[2]; z3 = zz[3];
            }
            // params for this f (L1/L2-hot after first block)
            float4 a0 = *(const float4*)(slx + f * 8), a1 = *(const float4*)(slx + f * 8 + 4);
            float4 b0 = *(const float4*)(ofx + f * 8), b1 = *(const float4*)(ofx + f * 8 + 4);
            float4 cc0 = *(const float4*)(slc + f * 8), cc1 = *(const float4*)(slc + f * 8 + 4);
            float4 d0 = *(const float4*)(ofc + f * 8), d1 = *(const float4*)(ofc + f * 8 + 4);
            float btf = bt[f], sf = s[f];
            float bcv = bc[f], bgv = bg[f];
            float zr[4] = { z0, z1, z2, z3 };
            #pragma unroll
            for (int r = 0; r < 4; r++) {
                float z = zr[r] + btf;
                float cvx = fmaf(z, a0.x, b0.x);
                cvx = fmaxf(cvx, fmaf(z, a0.y, b0.y));
                cvx = fmaxf(cvx, fmaf(z, a0.z, b0.z));
                cvx = fmaxf(cvx, fmaf(z, a0.w, b0.w));
                cvx = fmaxf(cvx, fmaf(z, a1.x, b1.x));
                cvx = fmaxf(cvx, fmaf(z, a1.y, b1.y));
                cvx = fmaxf(cvx, fmaf(z, a1.z, b1.z));
                cvx = fmaxf(cvx, fmaf(z, a1.w, b1.w));
                float ccv = fmaf(z, cc0.x, d0.x);
                ccv = fminf(ccv, fmaf(z, cc0.y, d0.y));
                ccv = fminf(ccv, fmaf(z, cc0.z, d0.z));
                ccv = fminf(ccv, fmaf(z, cc0.w, d0.w));
                ccv = fminf(ccv, fmaf(z, cc1.x, d1.x));
                ccv = fminf(ccv, fmaf(z, cc1.y, d1.y));
                ccv = fminf(ccv, fmaf(z, cc1.z, d1.z));
                ccv = fminf(ccv, fmaf(z, cc1.w, d1.w));
                float tv = sf * cvx + (1.0f - sf) * ccv;
                float cpre = accc[mi][ni][r] + bcv;
                float gpre = accg[mi][ni][r] + bgv;
                float g = sigm(gpre);
                float cla = gelu_f(cpre);
                int m = bm * 128 + mb + r;
                fused[(size_t)m * NF + f] = f2bf(g * tv + (1.0f - g) * cla);
            }
        }
    }
}

// ------------------------------------------------- kernel 5: GEMM2 (fused@Wd + bd)
__global__ __launch_bounds__(512, 4) void gemm2_kernel(
    const unsigned short* __restrict__ A,  // fused [T][1024]
    const unsigned short* __restrict__ Bt, // WdT [256][1024]
    const float* __restrict__ bd, float* __restrict__ out) {
    __shared__ __align__(16) unsigned short As[128 * LDSS];
    __shared__ __align__(16) unsigned short Bs[128 * LDSS];
    const int t = threadIdx.x;
    const int bm = blockIdx.x, bn = blockIdx.y;
    const int wave = t >> 6, lane = t & 63;
    const int wm = wave & 1, wn = wave >> 1;
    const int lr = lane & 15, quad = lane >> 4;
    const int srow = wave * 16 + (lane >> 2), scol = (lane & 3) << 3;
    const unsigned short* gA = A  + (size_t)(bm * 128 + srow) * NF + scol;
    const unsigned short* gB = Bt + (size_t)(bn * 128 + srow) * NF + scol;
    unsigned short* lA = &As[wave * 16 * LDSS];
    unsigned short* lB = &Bs[wave * 16 * LDSS];

    floatx4 acc[4][2];
    #pragma unroll
    for (int i = 0; i < 4; i++)
        #pragma unroll
        for (int j = 0; j < 2; j++) acc[i][j] = (floatx4)0.0f;

    for (int k0 = 0; k0 < NF; k0 += 32) {
        __syncthreads();
        g2lds16(gA + k0, lA);
        g2lds16(gB + k0, lB);
        __syncthreads();
        bf16x8 af[4], bf_[2];
        #pragma unroll
        for (int mi = 0; mi < 4; mi++)
            af[mi] = *(const bf16x8*)&As[(wm * 64 + mi * 16 + lr) * LDSS + quad * 8];
        #pragma unroll
        for (int ni = 0; ni < 2; ni++)
            bf_[ni] = *(const bf16x8*)&Bs[(wn * 32 + ni * 16 + lr) * LDSS + quad * 8];
        #pragma unroll
        for (int mi = 0; mi < 4; mi++)
            #pragma unroll
            for (int ni = 0; ni < 2; ni++)
                acc[mi][ni] = __builtin_amdgcn_mfma_f32_16x16x32_bf16(af[mi], bf_[ni], acc[mi][ni], 0, 0, 0);
    }
    #pragma unroll
    for (int mi = 0; mi < 4; mi++)
        #pragma unroll
        for (int ni = 0; ni < 2; ni++) {
            int n = bn * 128 + wn * 32 + ni * 16 + lr;
            float bdv = bd[n];
            #pragma unroll
            for (int r = 0; r < 4; r++) {
                int m = bm * 128 + wm * 64 + mi * 16 + quad * 4 + r;
                out[m * DM + n] = acc[mi][ni][r] + bdv;
            }
        }
}

// ------------------------------------------------------------- launcher
extern "C" void kernel_launch(void* const* d_in, const int* in_sizes, int n_in,
                              void* d_out, int out_size, void* d_ws, size_t ws_size,
                              hipStream_t stream) {
    const float* x     = (const float*)d_in[0];
    const float* Wt    = (const float*)d_in[1];
    const float* bt    = (const float*)d_in[2];
    const float* slx   = (const float*)d_in[3];
    const float* ofx   = (const float*)d_in[4];
    const float* slc   = (const float*)d_in[5];
    const float* ofc   = (const float*)d_in[6];
    const float* alpha = (const float*)d_in[7];
    const float* Wc    = (const float*)d_in[8];
    const float* bc    = (const float*)d_in[9];
    const float* Wg    = (const float*)d_in[10];
    const float* bg    = (const float*)d_in[11];
    const float* Wd    = (const float*)d_in[12];
    const float* bd    = (const float*)d_in[13];
    float* out = (float*)d_out;
    char* ws = (char*)d_ws;

    unsigned int* slot = (unsigned int*)(ws + O_SLOT);
    float* s           = (float*)(ws + O_S);
    unsigned short* Wct = (unsigned short*)(ws + O_WCT);
    unsigned short* Wgt = (unsigned short*)(ws + O_WGT);
    unsigned short* WdT = (unsigned short*)(ws + O_WDT);
    float* WtT          = (float*)(ws + O_WTT);
    unsigned short* xbf = (unsigned short*)(ws + O_XBF);
    int* counts         = (int*)(ws + O_CNT);
    int* cidx           = (int*)(ws + O_CIDX);
    float* cval         = (float*)(ws + O_CVAL);
    unsigned short* fused = (unsigned short*)(ws + O_FUSD);

    pack_kernel<<<1024, 256, 0, stream>>>(Wt, alpha, Wc, Wg, Wd, Wct, Wgt, WdT, WtT, s, slot);
    minmax_kernel<<<128, 256, 0, stream>>>(Wt, slot);
    cand_kernel<<<TTOK, 256, 0, stream>>>(x, slot, xbf, counts, cidx, cval);
    gemm1_kernel<<<dim3(TTOK / 128, NF / 128), 512, 0, stream>>>(
        xbf, Wct, Wgt, bc, bg, counts, cidx, cval, x, WtT, bt,
        slx, ofx, slc, ofc, s, fused);
    gemm2_kernel<<<dim3(TTOK / 128, DM / 128), 512, 0, stream>>>(fused, WdT, bd, out);
}